// Round 7
// baseline (495.638 us; speedup 1.0000x reference)
//
#include <hip/hip_runtime.h>

#define GI   768
#define HID  150
#define HPAD 160
#define DDIM 20

typedef __attribute__((ext_vector_type(8))) short v8s;
typedef __attribute__((ext_vector_type(4))) float f32x4;
typedef __attribute__((ext_vector_type(16))) float f32x16;

#define MFMA(A, B, C)   __builtin_amdgcn_mfma_f32_32x32x16_bf16(A, B, C, 0, 0, 0)
#define MFMA16(A, B, C) __builtin_amdgcn_mfma_f32_16x16x32_bf16(A, B, C, 0, 0, 0)

// round-to-nearest-even bf16 (cold path: weight prep)
__device__ __forceinline__ ushort bf16rn(float x) {
  unsigned u = __float_as_uint(x);
  return (ushort)((u + 0x7fffu + ((u >> 16) & 1u)) >> 16);
}
__device__ __forceinline__ void bsplit(float x, ushort& h, ushort& l) {
  h = bf16rn(x);
  float fh = __uint_as_float((unsigned)h << 16);
  l = bf16rn(x - fh);
}
// truncation split (hot path)
__device__ __forceinline__ void tsplit(float x, ushort& h, ushort& l) {
  unsigned u = __float_as_uint(x);
  h = (ushort)(u >> 16);
  float d = x - __uint_as_float(u & 0xffff0000u);
  l = (ushort)(__float_as_uint(d) >> 16);
}
__device__ __forceinline__ uint4 pack8(const ushort* v) {
  uint4 r;
  r.x = v[0] | ((unsigned)v[1] << 16); r.y = v[2] | ((unsigned)v[3] << 16);
  r.z = v[4] | ((unsigned)v[5] << 16); r.w = v[6] | ((unsigned)v[7] << 16);
  return r;
}
__device__ __forceinline__ v8s mk8(const ushort* v) {
  union { uint4 u; v8s s; } t;
  t.u = pack8(v);
  return t.s;
}

// ---------------- segment boundaries ------------------------------------------
__global__ void seg_kernel(const int* __restrict__ mI, int* __restrict__ segs,
                           int P, int S) {
  int m = blockIdx.x * 256 + threadIdx.x;
  if (m > S) return;
  int lo = 0, hi = P;
  while (lo < hi) { int mid = (lo + hi) >> 1; if (mI[mid] < m) lo = mid + 1; else hi = mid; }
  segs[m] = lo;
}

// ---------------- phi lookup tables: phiW[21][HPAD] f32 -----------------------
__global__ void phi_kernel(const float* __restrict__ de, const float* __restrict__ ge,
                           const float* __restrict__ se, const float* __restrict__ W1,
                           float* __restrict__ phiW) {
  int idx = blockIdx.x * 256 + threadIdx.x;
  if (idx >= 21 * HPAD) return;
  int row = idx / HPAD, h = idx % HPAD;
  float v = 0.f;
  if (h < HID) {
    const float* emb; int off;
    if (row < 10)      { emb = de + row * DDIM;        off = 0; }
    else if (row < 18) { emb = ge + (row - 10) * DDIM; off = DDIM; }
    else               { emb = se + (row - 18) * DDIM; off = 2 * DDIM; }
    for (int k = 0; k < DDIM; ++k) v += emb[k] * W1[(3 * GI + off + k) * HID + h];
  }
  phiW[row * HPAD + h] = v;
}

// ---------------- weight prep -------------------------------------------------
// WB[5][48][64][8]  (h1a, 32x32x16): h = c*32+(l&31), k = s*16+8*(l>>5)+j, W1c
// W16[20][24][64][8] (pre3, 16x16x32): col = ct*16+(l&15) over [A|B] 320,
//     k = s*32+8*(l>>4)+j
// W2B[5][10][64][8]  (score3, 32x32x16): h2 = rt*32+(l&31), k = s*16+8*(l>>5)+j, W2
#define NWB  (5 * 48 * 512)
#define NW16 (20 * 24 * 512)
#define NW2B (5 * 10 * 512)
__global__ void pad2_kernel(const float* __restrict__ W1, const float* __restrict__ W2,
                            const float* __restrict__ b1, const float* __restrict__ b2,
                            const float* __restrict__ W3,
                            ushort* __restrict__ WBhi, ushort* __restrict__ WBlo,
                            ushort* __restrict__ W16hi, ushort* __restrict__ W16lo,
                            ushort* __restrict__ W2Bhi, ushort* __restrict__ W2Blo,
                            float* __restrict__ b1p, float2* __restrict__ b2w3) {
  int idx = blockIdx.x * 256 + threadIdx.x;
  if (idx < NWB) {
    int c = idx / (48 * 512); int r1 = idx % (48 * 512);
    int s = r1 / 512; int r2 = r1 % 512;
    int l = r2 / 8, j = r2 % 8;
    int h = c * 32 + (l & 31);
    int k = s * 16 + 8 * (l >> 5) + j;
    float x = (h < HID) ? W1[(size_t)(2 * GI + k) * HID + h] : 0.f;
    ushort hh, ll; bsplit(x, hh, ll);
    WBhi[idx] = hh; WBlo[idx] = ll; return;
  }
  idx -= NWB;
  if (idx < NW16) {
    int ct = idx / (24 * 512); int r1 = idx % (24 * 512);
    int s = r1 / 512; int r2 = r1 % 512;
    int l = r2 / 8, j = r2 % 8;
    int col = ct * 16 + (l & 15);
    int k = s * 32 + 8 * (l >> 4) + j;
    int seg = col / HPAD, h = col % HPAD;
    float x = (h < HID) ? W1[(size_t)(seg * GI + k) * HID + h] : 0.f;
    ushort hh, ll; bsplit(x, hh, ll);
    W16hi[idx] = hh; W16lo[idx] = ll; return;
  }
  idx -= NW16;
  if (idx < NW2B) {
    int rt = idx / (10 * 512); int r1 = idx % (10 * 512);
    int s = r1 / 512; int r2 = r1 % 512;
    int l = r2 / 8, j = r2 % 8;
    int h2 = rt * 32 + (l & 31);
    int k = s * 16 + 8 * (l >> 5) + j;
    float x = (k < HID && h2 < HID) ? W2[(size_t)k * HID + h2] : 0.f;
    ushort hh, ll; bsplit(x, hh, ll);
    W2Bhi[idx] = hh; W2Blo[idx] = ll; return;
  }
  idx -= NW2B;
  if (idx < HPAD) { b1p[idx] = (idx < HID) ? b1[idx] : 0.f; return; }
  idx -= HPAD;
  if (idx < HPAD) {
    b2w3[idx] = make_float2((idx < HID) ? b2[idx] : 0.f, (idx < HID) ? W3[idx] : 0.f);
    return;
  }
}

// ---------------- pre3: pre[s][0:320] = g[s]@[W1a|W1b], 16x16 tiles, 1 wave ---
__global__ __launch_bounds__(64, 4) void pre3_kernel(
    const float* __restrict__ g, const ushort* __restrict__ W16hi,
    const ushort* __restrict__ W16lo, float* __restrict__ pre, int S) {
  const int lane = threadIdx.x;
  const int ct = blockIdx.x;            // 20 col-tiles over 320
  const int row0 = blockIdx.y * 16;
  int srow = row0 + (lane & 15); if (srow >= S) srow = S - 1;
  const float* gp = g + (size_t)srow * GI + 8 * (lane >> 4);
  const ushort* wph = W16hi + ((size_t)ct * 24 * 64 + lane) * 8;
  const ushort* wpl = W16lo + ((size_t)ct * 24 * 64 + lane) * 8;

  f32x4 acc = {};
#pragma unroll 2
  for (int s = 0; s < 24; ++s) {
    const float4 a0 = *(const float4*)(gp + s * 32);
    const float4 a1 = *(const float4*)(gp + s * 32 + 4);
    const v8s bh = *(const v8s*)(wph + (size_t)s * 512);
    const v8s bl = *(const v8s*)(wpl + (size_t)s * 512);
    float xr[8] = {a0.x, a0.y, a0.z, a0.w, a1.x, a1.y, a1.z, a1.w};
    ushort hs[8], ls[8];
#pragma unroll
    for (int j = 0; j < 8; ++j) tsplit(xr[j], hs[j], ls[j]);
    const v8s ah = mk8(hs), al = mk8(ls);
    acc = MFMA16(ah, bh, acc);
    acc = MFMA16(al, bh, acc);
    acc = MFMA16(ah, bl, acc);
  }
  const int col = ct * 16 + (lane & 15);
#pragma unroll
  for (int r = 0; r < 4; ++r) {
    int sr = row0 + (lane >> 4) * 4 + r;
    if (sr < S) pre[(size_t)sr * 320 + col] = acc[r];
  }
}

// ---------------- h1a: per-pair h1 GEMM, 1 wave, no LDS, deep prefetch --------
__global__ __launch_bounds__(64, 2) void h1a_kernel(
    const float* __restrict__ g, const float* __restrict__ pre,
    const float* __restrict__ phiW,
    const ushort* __restrict__ WBhi, const ushort* __restrict__ WBlo,
    const float* __restrict__ b1p,
    const int* __restrict__ mI, const int* __restrict__ aI,
    const int* __restrict__ db, const int* __restrict__ ge, const int* __restrict__ sp,
    ushort* __restrict__ h1hi, ushort* __restrict__ h1lo, int P) {
  const int lane = threadIdx.x;
  const int lcol = lane & 31, half = lane >> 5;

  // XCD-bijective chunked swizzle (m204): consecutive wg share sorted i-rows
  const int nwg = gridDim.x;
  const int orig = blockIdx.x;
  const int xcd = orig & 7, idx8 = orig >> 3;
  const int qq = nwg >> 3, rr = nwg & 7;
  const int wg = (xcd < rr ? xcd * (qq + 1) : rr * (qq + 1) + (xcd - rr) * qq) + idx8;
  const int p0 = wg * 32;

  const int myp = p0 + lcol;
  const int iA = mI[myp], jA = aI[myp];
  const int rdL = db[myp], rgL = 10 + ge[myp], rsL = 18 + sp[myp];

  const float* gi = g + (size_t)iA * GI + 8 * half;
  const float* gj = g + (size_t)jA * GI + 8 * half;

  f32x16 acc[5];
  {
    f32x16 z = {};
#pragma unroll
    for (int c = 0; c < 5; ++c) acc[c] = z;
  }

  // prologue: step-0 operands in registers
  float4 A0 = *(const float4*)(gi);
  float4 A1 = *(const float4*)(gi + 4);
  float4 B0 = *(const float4*)(gj);
  float4 B1 = *(const float4*)(gj + 4);
  v8s wh[5], wl[5];
#pragma unroll
  for (int c = 0; c < 5; ++c) {
    const size_t o = ((size_t)(c * 48) * 64 + lane) * 8;
    wh[c] = *(const v8s*)(WBhi + o);
    wl[c] = *(const v8s*)(WBlo + o);
  }

#pragma unroll 2
  for (int s = 0; s < 48; ++s) {
    // issue next-step loads BEFORE this step's compute (stay in flight)
    const int sn = (s < 47) ? s + 1 : 47;
    const int dn = sn * 16;
    const float4 nA0 = *(const float4*)(gi + dn);
    const float4 nA1 = *(const float4*)(gi + dn + 4);
    const float4 nB0 = *(const float4*)(gj + dn);
    const float4 nB1 = *(const float4*)(gj + dn + 4);
    v8s nwh[5], nwl[5];
#pragma unroll
    for (int c = 0; c < 5; ++c) {
      const size_t o = ((size_t)(c * 48 + sn) * 64 + lane) * 8;
      nwh[c] = *(const v8s*)(WBhi + o);
      nwl[c] = *(const v8s*)(WBlo + o);
    }
    // current step: product, split, 15 MFMAs
    float xr[8] = {A0.x * B0.x, A0.y * B0.y, A0.z * B0.z, A0.w * B0.w,
                   A1.x * B1.x, A1.y * B1.y, A1.z * B1.z, A1.w * B1.w};
    ushort hs[8], ls[8];
#pragma unroll
    for (int j = 0; j < 8; ++j) tsplit(xr[j], hs[j], ls[j]);
    const v8s ah = mk8(hs), al = mk8(ls);
#pragma unroll
    for (int c = 0; c < 5; ++c) {
      acc[c] = MFMA(ah, wh[c], acc[c]);
      acc[c] = MFMA(al, wh[c], acc[c]);
      acc[c] = MFMA(ah, wl[c], acc[c]);
    }
    // rotate
    A0 = nA0; A1 = nA1; B0 = nB0; B1 = nB1;
#pragma unroll
    for (int c = 0; c < 5; ++c) { wh[c] = nwh[c]; wl[c] = nwl[c]; }
  }

  // epilogue: + pre_i + pre_j + phi + b1, relu, split to bf16 hi/lo, store
#pragma unroll
  for (int q = 0; q < 16; ++q) {
    const int rr2 = (q & 3) + 8 * (q >> 2) + 4 * half;
    const int pI = __shfl(iA, rr2);
    const int pJ = __shfl(jA, rr2);
    const int rd = __shfl(rdL, rr2), rg = __shfl(rgL, rr2), rs = __shfl(rsL, rr2);
    const float* preI = pre + (size_t)pI * 320;
    const float* preJ = pre + (size_t)pJ * 320 + 160;
    const size_t prow = (size_t)(p0 + rr2) * 160;
#pragma unroll
    for (int c = 0; c < 5; ++c) {
      const int col = c * 32 + lcol;
      float v = acc[c][q] + b1p[col] + preI[col] + preJ[col]
              + phiW[rd * HPAD + col] + phiW[rg * HPAD + col] + phiW[rs * HPAD + col];
      v = fmaxf(v, 0.f);
      ushort hh, ll; tsplit(v, hh, ll);
      h1hi[prow + col] = hh;
      h1lo[prow + col] = ll;
    }
  }
}

// ---------------- score3: score = relu(h1@W2+b2)@W3 + b3, 1 wave/block -------
__global__ __launch_bounds__(64, 3) void score3_kernel(
    const ushort* __restrict__ h1hi, const ushort* __restrict__ h1lo,
    const ushort* __restrict__ W2Bhi, const ushort* __restrict__ W2Blo,
    const float2* __restrict__ b2w3, const float* __restrict__ b3,
    float* __restrict__ sOut, int P) {
  const int lane = threadIdx.x;
  const int lcol = lane & 31, half = lane >> 5;
  const int p0 = blockIdx.x * 32;

  const ushort* hh = h1hi + (size_t)(p0 + lcol) * 160 + 8 * half;
  const ushort* hl = h1lo + (size_t)(p0 + lcol) * 160 + 8 * half;

  f32x16 acc[5];
  {
    f32x16 z = {};
#pragma unroll
    for (int r = 0; r < 5; ++r) acc[r] = z;
  }

#pragma unroll 2
  for (int s = 0; s < 10; ++s) {
    const v8s bh = *(const v8s*)(hh + s * 16);
    const v8s bl = *(const v8s*)(hl + s * 16);
#pragma unroll
    for (int r = 0; r < 5; ++r) {
      const size_t o = ((size_t)(r * 10 + s) * 64 + lane) * 8;
      const v8s ah = *(const v8s*)(W2Bhi + o);
      const v8s al = *(const v8s*)(W2Blo + o);
      acc[r] = MFMA(ah, bh, acc[r]);
      acc[r] = MFMA(al, bh, acc[r]);
      acc[r] = MFMA(ah, bl, acc[r]);
    }
  }

  float part = 0.f;
#pragma unroll
  for (int r = 0; r < 5; ++r) {
#pragma unroll
    for (int q = 0; q < 16; ++q) {
      const int h2 = r * 32 + (q & 3) + 8 * (q >> 2) + 4 * half;
      const float2 bw = b2w3[h2];
      part += fmaxf(acc[r][q] + bw.x, 0.f) * bw.y;
    }
  }
  part += __shfl_xor(part, 32);
  if (lane < 32) sOut[p0 + lane] = part + b3[0];
}

// ---------------- mid: segment softmax -> weighted -> gated g update ----------
__global__ void mid_kernel(const float* __restrict__ g, const float* __restrict__ s1,
                           const int* __restrict__ segs, const int* __restrict__ aI,
                           const float* __restrict__ Wf, const float* __restrict__ bf,
                           float* __restrict__ g2) {
  const int m = blockIdx.x;
  const int t = threadIdx.x;  // 256
  const int st = segs[m], en = segs[m + 1], n = en - st;
  if (n == 0) {
    for (int d = t; d < GI; d += 256) g2[m * GI + d] = g[m * GI + d];
    return;
  }
  __shared__ float red[256];
  float mx = -INFINITY;
  for (int p = st + t; p < en; p += 256) mx = fmaxf(mx, s1[p]);
  red[t] = mx; __syncthreads();
  for (int s = 128; s > 0; s >>= 1) { if (t < s) red[t] = fmaxf(red[t], red[t + s]); __syncthreads(); }
  mx = red[0]; __syncthreads();
  float sm = 0.f;
  for (int p = st + t; p < en; p += 256) sm += expf(s1[p] - mx);
  red[t] = sm; __syncthreads();
  for (int s = 128; s > 0; s >>= 1) { if (t < s) red[t] += red[t + s]; __syncthreads(); }
  const float denom = red[0]; __syncthreads();
  float wv[3] = {0.f, 0.f, 0.f};
  for (int p = st; p < en; ++p) {
    float e = expf(s1[p] - mx);
    const float* gj = g + (size_t)aI[p] * GI;
#pragma unroll
    for (int u = 0; u < 3; ++u) wv[u] += e * gj[t + u * 256];
  }
#pragma unroll
  for (int u = 0; u < 3; ++u) wv[u] /= denom;
  float part = 0.f;
#pragma unroll
  for (int u = 0; u < 3; ++u) {
    int d = t + u * 256;
    part += g[m * GI + d] * Wf[d] + wv[u] * Wf[GI + d];
  }
  red[t] = part; __syncthreads();
  for (int s = 128; s > 0; s >>= 1) { if (t < s) red[t] += red[t + s]; __syncthreads(); }
  const float f = 1.f / (1.f + expf(-(red[0] + bf[0])));
#pragma unroll
  for (int u = 0; u < 3; ++u) {
    int d = t + u * 256;
    g2[m * GI + d] = f * (float)m + (1.f - f) * wv[u];
  }
}

// ---------------- coref_scores[p] = ms[i] + ms[j] + s2[p] ---------------------
__global__ void coref_kernel(const float* __restrict__ ms, const float* __restrict__ s2,
                             const int* __restrict__ mI, const int* __restrict__ aI,
                             float* __restrict__ out, int P) {
  int p = blockIdx.x * 256 + threadIdx.x;
  if (p >= P) return;
  out[p] = ms[mI[p]] + ms[aI[p]] + s2[p];
}

// ---------------- final segment softmax with epsilon --------------------------
__global__ void final_kernel(const float* __restrict__ c, const int* __restrict__ segs,
                             float* __restrict__ pairP, float* __restrict__ epsP) {
  const int m = blockIdx.x;
  const int t = threadIdx.x;  // 256
  const int st = segs[m], en = segs[m + 1], n = en - st;
  __shared__ float red[256];
  float mx = -INFINITY;
  for (int p = st + t; p < en; p += 256) mx = fmaxf(mx, c[p]);
  red[t] = mx; __syncthreads();
  for (int s = 128; s > 0; s >>= 1) { if (t < s) red[t] = fmaxf(red[t], red[t + s]); __syncthreads(); }
  mx = red[0]; __syncthreads();
  const float m2 = (n > 0) ? fmaxf(mx, 0.f) : 0.f;
  float sm = 0.f;
  for (int p = st + t; p < en; p += 256) sm += expf(c[p] - m2);
  red[t] = sm; __syncthreads();
  for (int s = 128; s > 0; s >>= 1) { if (t < s) red[t] += red[t + s]; __syncthreads(); }
  const float denom = red[0] + expf(-m2);
  for (int p = st + t; p < en; p += 256) pairP[p] = expf(c[p] - m2) / denom;
  if (t == 0) epsP[m] = expf(-m2) / denom;
}

extern "C" void kernel_launch(void* const* d_in, const int* in_sizes, int n_in,
                              void* d_out, int out_size, void* d_ws, size_t ws_size,
                              hipStream_t stream) {
  const float* g_i  = (const float*)d_in[0];
  const float* ms   = (const float*)d_in[1];
  const int*   mI   = (const int*)d_in[2];
  const int*   aI   = (const int*)d_in[3];
  const int*   db   = (const int*)d_in[4];
  const int*   ge   = (const int*)d_in[5];
  const int*   sp   = (const int*)d_in[6];
  const float* de   = (const float*)d_in[7];
  const float* gemb = (const float*)d_in[8];
  const float* semb = (const float*)d_in[9];
  const float* W1   = (const float*)d_in[10];
  const float* b1   = (const float*)d_in[11];
  const float* W2   = (const float*)d_in[12];
  const float* b2   = (const float*)d_in[13];
  const float* W3   = (const float*)d_in[14];
  const float* b3   = (const float*)d_in[15];
  const float* Wf   = (const float*)d_in[16];
  const float* bf   = (const float*)d_in[17];

  const int S = in_sizes[0] / GI;
  const int P = in_sizes[2];
  float* out = (float*)d_out;                 // [coref P | pairP P | epsP S]

  char* ws = (char*)d_ws;
  size_t off = 0;
  auto take = [&](size_t bytes) -> char* {
    char* p = ws + off;
    off = (off + bytes + 15) & ~(size_t)15;
    return p;
  };
  int*    segs  = (int*)   take((size_t)(S + 1) * 4);
  float*  phiW  = (float*) take((size_t)21 * HPAD * 4);
  float*  pre   = (float*) take((size_t)S * 320 * 4);
  float*  g2    = (float*) take((size_t)S * GI * 4);
  float*  s1    = (float*) take((size_t)P * 4);
  float*  s2    = (float*) take((size_t)P * 4);
  ushort* WBhi  = (ushort*)take((size_t)NWB * 2);
  ushort* WBlo  = (ushort*)take((size_t)NWB * 2);
  ushort* W16hi = (ushort*)take((size_t)NW16 * 2);
  ushort* W16lo = (ushort*)take((size_t)NW16 * 2);
  ushort* W2Bhi = (ushort*)take((size_t)NW2B * 2);
  ushort* W2Blo = (ushort*)take((size_t)NW2B * 2);
  float*  b1p   = (float*) take((size_t)HPAD * 4);
  float2* b2w3  = (float2*)take((size_t)HPAD * 8);
  ushort* h1hi  = (ushort*)take((size_t)P * 160 * 2);
  ushort* h1lo  = (ushort*)take((size_t)P * 160 * 2);

  const int gridSeg = (S + 1 + 255) / 256;
  const int gridPhi = (21 * HPAD + 255) / 256;
  const int padTot  = NWB + NW16 + NW2B + 2 * HPAD;
  const int gridPad = (padTot + 255) / 256;
  const dim3 gridPre(20, (S + 15) / 16);
  const int gridH   = P / 32;          // P % 32 == 0
  const int gridCor = (P + 255) / 256;

  seg_kernel<<<gridSeg, 256, 0, stream>>>(mI, segs, P, S);
  phi_kernel<<<gridPhi, 256, 0, stream>>>(de, gemb, semb, W1, phiW);
  pad2_kernel<<<gridPad, 256, 0, stream>>>(W1, W2, b1, b2, W3, WBhi, WBlo,
                                           W16hi, W16lo, W2Bhi, W2Blo, b1p, b2w3);

  // iteration 1 (g = g_i)
  pre3_kernel<<<gridPre, 64, 0, stream>>>(g_i, W16hi, W16lo, pre, S);
  h1a_kernel<<<gridH, 64, 0, stream>>>(g_i, pre, phiW, WBhi, WBlo, b1p,
                                       mI, aI, db, ge, sp, h1hi, h1lo, P);
  score3_kernel<<<gridH, 64, 0, stream>>>(h1hi, h1lo, W2Bhi, W2Blo, b2w3, b3, s1, P);
  mid_kernel<<<S, 256, 0, stream>>>(g_i, s1, segs, aI, Wf, bf, g2);

  // iteration 2 (g = g2)
  pre3_kernel<<<gridPre, 64, 0, stream>>>(g2, W16hi, W16lo, pre, S);
  h1a_kernel<<<gridH, 64, 0, stream>>>(g2, pre, phiW, WBhi, WBlo, b1p,
                                       mI, aI, db, ge, sp, h1hi, h1lo, P);
  score3_kernel<<<gridH, 64, 0, stream>>>(h1hi, h1lo, W2Bhi, W2Blo, b2w3, b3, s2, P);

  // outputs
  coref_kernel<<<gridCor, 256, 0, stream>>>(ms, s2, mI, aI, out, P);
  final_kernel<<<S, 256, 0, stream>>>(out, segs, out + P, out + 2 * (size_t)P);
}

// Round 8
// 472.269 us; speedup vs baseline: 1.0495x; 1.0495x over previous
//
#include <hip/hip_runtime.h>

#define GI   768
#define HID  150
#define HPAD 160
#define DDIM 20

typedef __attribute__((ext_vector_type(8))) short v8s;
typedef __attribute__((ext_vector_type(4))) float f32x4;
typedef __attribute__((ext_vector_type(16))) float f32x16;

#define MFMA(A, B, C)   __builtin_amdgcn_mfma_f32_32x32x16_bf16(A, B, C, 0, 0, 0)
#define MFMA16(A, B, C) __builtin_amdgcn_mfma_f32_16x16x32_bf16(A, B, C, 0, 0, 0)

// round-to-nearest-even bf16 (cold path: weight prep)
__device__ __forceinline__ ushort bf16rn(float x) {
  unsigned u = __float_as_uint(x);
  return (ushort)((u + 0x7fffu + ((u >> 16) & 1u)) >> 16);
}
__device__ __forceinline__ void bsplit(float x, ushort& h, ushort& l) {
  h = bf16rn(x);
  float fh = __uint_as_float((unsigned)h << 16);
  l = bf16rn(x - fh);
}
// truncation split (hot path)
__device__ __forceinline__ void tsplit(float x, ushort& h, ushort& l) {
  unsigned u = __float_as_uint(x);
  h = (ushort)(u >> 16);
  float d = x - __uint_as_float(u & 0xffff0000u);
  l = (ushort)(__float_as_uint(d) >> 16);
}
__device__ __forceinline__ uint4 pack8(const ushort* v) {
  uint4 r;
  r.x = v[0] | ((unsigned)v[1] << 16); r.y = v[2] | ((unsigned)v[3] << 16);
  r.z = v[4] | ((unsigned)v[5] << 16); r.w = v[6] | ((unsigned)v[7] << 16);
  return r;
}
__device__ __forceinline__ v8s mk8(const ushort* v) {
  union { uint4 u; v8s s; } t;
  t.u = pack8(v);
  return t.s;
}

// async global->LDS, 16B per lane (per-lane gsrc, wave-uniform LDS base)
__device__ __forceinline__ void stage16(const ushort* gsrc, ushort* ldst) {
  __builtin_amdgcn_global_load_lds(
      (const __attribute__((address_space(1))) unsigned int*)(const void*)gsrc,
      (__attribute__((address_space(3))) unsigned int*)(void*)ldst, 16, 0, 0);
}

// ---------------- segment boundaries ------------------------------------------
__global__ void seg_kernel(const int* __restrict__ mI, int* __restrict__ segs,
                           int P, int S) {
  int m = blockIdx.x * 256 + threadIdx.x;
  if (m > S) return;
  int lo = 0, hi = P;
  while (lo < hi) { int mid = (lo + hi) >> 1; if (mI[mid] < m) lo = mid + 1; else hi = mid; }
  segs[m] = lo;
}

// ---------------- phi lookup tables: phiW[21][HPAD] f32 -----------------------
__global__ void phi_kernel(const float* __restrict__ de, const float* __restrict__ ge,
                           const float* __restrict__ se, const float* __restrict__ W1,
                           float* __restrict__ phiW) {
  int idx = blockIdx.x * 256 + threadIdx.x;
  if (idx >= 21 * HPAD) return;
  int row = idx / HPAD, h = idx % HPAD;
  float v = 0.f;
  if (h < HID) {
    const float* emb; int off;
    if (row < 10)      { emb = de + row * DDIM;        off = 0; }
    else if (row < 18) { emb = ge + (row - 10) * DDIM; off = DDIM; }
    else               { emb = se + (row - 18) * DDIM; off = 2 * DDIM; }
    for (int k = 0; k < DDIM; ++k) v += emb[k] * W1[(3 * GI + off + k) * HID + h];
  }
  phiW[row * HPAD + h] = v;
}

// ---------------- weight prep -------------------------------------------------
// WS[48][10][64][8] (h1b): per K-step s, 10 contiguous 1KB fragments.
//   frag fi: c = fi>>1, hl = fi&1 (0=hi,1=lo); h = c*32+(l&31), k = s*16+8*(l>>5)+j
// W16[20][24][64][8] (pre3, 16x16x32): col = ct*16+(l&15), k = s*32+8*(l>>4)+j
// W2B[5][10][64][8]  (score3): h2 = rt*32+(l&31), k = s*16+8*(l>>5)+j
#define NWS  (48 * 10 * 512)
#define NW16 (20 * 24 * 512)
#define NW2B (5 * 10 * 512)
__global__ void pad2_kernel(const float* __restrict__ W1, const float* __restrict__ W2,
                            const float* __restrict__ b1, const float* __restrict__ b2,
                            const float* __restrict__ W3,
                            ushort* __restrict__ WS,
                            ushort* __restrict__ W16hi, ushort* __restrict__ W16lo,
                            ushort* __restrict__ W2Bhi, ushort* __restrict__ W2Blo,
                            float* __restrict__ b1p, float2* __restrict__ b2w3) {
  int idx = blockIdx.x * 256 + threadIdx.x;
  if (idx < NWS) {
    int s = idx / (10 * 512); int r1 = idx % (10 * 512);
    int fi = r1 / 512; int r2 = r1 % 512;
    int l = r2 / 8, j = r2 % 8;
    int c = fi >> 1, hl = fi & 1;
    int h = c * 32 + (l & 31);
    int k = s * 16 + 8 * (l >> 5) + j;
    float x = (h < HID) ? W1[(size_t)(2 * GI + k) * HID + h] : 0.f;
    ushort hh, ll; bsplit(x, hh, ll);
    WS[idx] = hl ? ll : hh; return;
  }
  idx -= NWS;
  if (idx < NW16) {
    int ct = idx / (24 * 512); int r1 = idx % (24 * 512);
    int s = r1 / 512; int r2 = r1 % 512;
    int l = r2 / 8, j = r2 % 8;
    int col = ct * 16 + (l & 15);
    int k = s * 32 + 8 * (l >> 4) + j;
    int seg = col / HPAD, h = col % HPAD;
    float x = (h < HID) ? W1[(size_t)(seg * GI + k) * HID + h] : 0.f;
    ushort hh, ll; bsplit(x, hh, ll);
    W16hi[idx] = hh; W16lo[idx] = ll; return;
  }
  idx -= NW16;
  if (idx < NW2B) {
    int rt = idx / (10 * 512); int r1 = idx % (10 * 512);
    int s = r1 / 512; int r2 = r1 % 512;
    int l = r2 / 8, j = r2 % 8;
    int h2 = rt * 32 + (l & 31);
    int k = s * 16 + 8 * (l >> 5) + j;
    float x = (k < HID && h2 < HID) ? W2[(size_t)k * HID + h2] : 0.f;
    ushort hh, ll; bsplit(x, hh, ll);
    W2Bhi[idx] = hh; W2Blo[idx] = ll; return;
  }
  idx -= NW2B;
  if (idx < HPAD) { b1p[idx] = (idx < HID) ? b1[idx] : 0.f; return; }
  idx -= HPAD;
  if (idx < HPAD) {
    b2w3[idx] = make_float2((idx < HID) ? b2[idx] : 0.f, (idx < HID) ? W3[idx] : 0.f);
    return;
  }
}

// ---------------- pre3: pre[s][0:320] = g[s]@[W1a|W1b], 16x16 tiles, 1 wave ---
__global__ __launch_bounds__(64, 4) void pre3_kernel(
    const float* __restrict__ g, const ushort* __restrict__ W16hi,
    const ushort* __restrict__ W16lo, float* __restrict__ pre, int S) {
  const int lane = threadIdx.x;
  const int ct = blockIdx.x;            // 20 col-tiles over 320
  const int row0 = blockIdx.y * 16;
  int srow = row0 + (lane & 15); if (srow >= S) srow = S - 1;
  const float* gp = g + (size_t)srow * GI + 8 * (lane >> 4);
  const ushort* wph = W16hi + ((size_t)ct * 24 * 64 + lane) * 8;
  const ushort* wpl = W16lo + ((size_t)ct * 24 * 64 + lane) * 8;

  f32x4 acc = {};
#pragma unroll 2
  for (int s = 0; s < 24; ++s) {
    const float4 a0 = *(const float4*)(gp + s * 32);
    const float4 a1 = *(const float4*)(gp + s * 32 + 4);
    const v8s bh = *(const v8s*)(wph + (size_t)s * 512);
    const v8s bl = *(const v8s*)(wpl + (size_t)s * 512);
    float xr[8] = {a0.x, a0.y, a0.z, a0.w, a1.x, a1.y, a1.z, a1.w};
    ushort hs[8], ls[8];
#pragma unroll
    for (int j = 0; j < 8; ++j) tsplit(xr[j], hs[j], ls[j]);
    const v8s ah = mk8(hs), al = mk8(ls);
    acc = MFMA16(ah, bh, acc);
    acc = MFMA16(al, bh, acc);
    acc = MFMA16(ah, bl, acc);
  }
  const int col = ct * 16 + (lane & 15);
#pragma unroll
  for (int r = 0; r < 4; ++r) {
    int sr = row0 + (lane >> 4) * 4 + r;
    if (sr < S) pre[(size_t)sr * 320 + col] = acc[r];
  }
}

// ---------------- h1b: 4-wave block, W staged through LDS (shared), 128 pairs -
__global__ __launch_bounds__(256, 3) void h1b_kernel(
    const float* __restrict__ g, const float* __restrict__ pre,
    const float* __restrict__ phiW, const ushort* __restrict__ WS,
    const float* __restrict__ b1p,
    const int* __restrict__ mI, const int* __restrict__ aI,
    const int* __restrict__ db, const int* __restrict__ ge, const int* __restrict__ sp,
    ushort* __restrict__ h1hi, ushort* __restrict__ h1lo, int P) {
  __shared__ ushort wbuf[2][10 * 512];     // 2 x 10KB double buffer

  const int t = threadIdx.x;
  const int lane = t & 63, wv = t >> 6;
  const int lcol = lane & 31, half = lane >> 5;

  // XCD-bijective chunked swizzle (m204)
  const int nwg = gridDim.x;
  const int orig = blockIdx.x;
  const int xcd = orig & 7, idx8 = orig >> 3;
  const int qq = nwg >> 3, rq = nwg & 7;
  const int wg = (xcd < rq ? xcd * (qq + 1) : rq * (qq + 1) + (xcd - rq) * qq) + idx8;
  const int p0w = wg * 128 + wv * 32;      // this wave's 32 pairs

  const int myp = p0w + lcol;
  const int iA = mI[myp], jA = aI[myp];
  const int rdL = db[myp], rgL = 10 + ge[myp], rsL = 18 + sp[myp];

  const float* gi = g + (size_t)iA * GI + 8 * half;
  const float* gj = g + (size_t)jA * GI + 8 * half;

  // stage frag assignment: wave wv stages {2wv, 2wv+1} (+ {8+wv} for wv<2)
  const int f0 = 2 * wv, f1 = 2 * wv + 1;
  const int f2 = (wv < 2) ? 8 + wv : -1;

  f32x16 acc[5];
  {
    f32x16 z = {};
#pragma unroll
    for (int c = 0; c < 5; ++c) acc[c] = z;
  }

  // prologue: stage step 0
  {
    const ushort* base = WS + (size_t)0 * 10 * 512;
    stage16(base + f0 * 512 + lane * 8, &wbuf[0][f0 * 512]);
    stage16(base + f1 * 512 + lane * 8, &wbuf[0][f1 * 512]);
    if (f2 >= 0) stage16(base + f2 * 512 + lane * 8, &wbuf[0][f2 * 512]);
  }
  asm volatile("s_waitcnt vmcnt(0)" ::: "memory");
  __syncthreads();

  int cur = 0;
#pragma unroll 2
  for (int s = 0; s < 48; ++s) {
    // stage next step into the other buffer (in flight across this step)
    if (s + 1 < 48) {
      const ushort* base = WS + (size_t)(s + 1) * 10 * 512;
      ushort* dst = wbuf[cur ^ 1];
      stage16(base + f0 * 512 + lane * 8, dst + f0 * 512);
      stage16(base + f1 * 512 + lane * 8, dst + f1 * 512);
      if (f2 >= 0) stage16(base + f2 * 512 + lane * 8, dst + f2 * 512);
    }
    // A-side: per-lane g gather, product, split (round-6 proven structure)
    const int d0 = s * 16;
    const float4 a0 = *(const float4*)(gi + d0);
    const float4 a1 = *(const float4*)(gi + d0 + 4);
    const float4 b0 = *(const float4*)(gj + d0);
    const float4 b1v = *(const float4*)(gj + d0 + 4);
    float xr[8] = {a0.x * b0.x, a0.y * b0.y, a0.z * b0.z, a0.w * b0.w,
                   a1.x * b1v.x, a1.y * b1v.y, a1.z * b1v.z, a1.w * b1v.w};
    ushort hs[8], ls[8];
#pragma unroll
    for (int j = 0; j < 8; ++j) tsplit(xr[j], hs[j], ls[j]);
    const v8s ah = mk8(hs), al = mk8(ls);
    // B-side from LDS, 3 MFMAs per c
    const ushort* wb = wbuf[cur];
#pragma unroll
    for (int c = 0; c < 5; ++c) {
      const v8s wh = *(const v8s*)(wb + (2 * c) * 512 + lane * 8);
      const v8s wl = *(const v8s*)(wb + (2 * c + 1) * 512 + lane * 8);
      acc[c] = MFMA(ah, wh, acc[c]);
      acc[c] = MFMA(al, wh, acc[c]);
      acc[c] = MFMA(ah, wl, acc[c]);
    }
    asm volatile("s_waitcnt vmcnt(0)" ::: "memory");
    __syncthreads();
    cur ^= 1;
  }

  // epilogue: + pre_i + pre_j + phi + b1, relu, split to bf16 hi/lo, store
#pragma unroll
  for (int q = 0; q < 16; ++q) {
    const int rr2 = (q & 3) + 8 * (q >> 2) + 4 * half;
    const int pI = __shfl(iA, rr2);
    const int pJ = __shfl(jA, rr2);
    const int rd = __shfl(rdL, rr2), rg = __shfl(rgL, rr2), rs = __shfl(rsL, rr2);
    const float* preI = pre + (size_t)pI * 320;
    const float* preJ = pre + (size_t)pJ * 320 + 160;
    const size_t prow = (size_t)(p0w + rr2) * 160;
#pragma unroll
    for (int c = 0; c < 5; ++c) {
      const int col = c * 32 + lcol;
      float v = acc[c][q] + b1p[col] + preI[col] + preJ[col]
              + phiW[rd * HPAD + col] + phiW[rg * HPAD + col] + phiW[rs * HPAD + col];
      v = fmaxf(v, 0.f);
      ushort hh, ll; tsplit(v, hh, ll);
      h1hi[prow + col] = hh;
      h1lo[prow + col] = ll;
    }
  }
}

// ---------------- score3: score = relu(h1@W2+b2)@W3 + b3, 1 wave/block -------
__global__ __launch_bounds__(64, 3) void score3_kernel(
    const ushort* __restrict__ h1hi, const ushort* __restrict__ h1lo,
    const ushort* __restrict__ W2Bhi, const ushort* __restrict__ W2Blo,
    const float2* __restrict__ b2w3, const float* __restrict__ b3,
    float* __restrict__ sOut, int P) {
  const int lane = threadIdx.x;
  const int lcol = lane & 31, half = lane >> 5;
  const int p0 = blockIdx.x * 32;

  const ushort* hh = h1hi + (size_t)(p0 + lcol) * 160 + 8 * half;
  const ushort* hl = h1lo + (size_t)(p0 + lcol) * 160 + 8 * half;

  f32x16 acc[5];
  {
    f32x16 z = {};
#pragma unroll
    for (int r = 0; r < 5; ++r) acc[r] = z;
  }

#pragma unroll 2
  for (int s = 0; s < 10; ++s) {
    const v8s bh = *(const v8s*)(hh + s * 16);
    const v8s bl = *(const v8s*)(hl + s * 16);
#pragma unroll
    for (int r = 0; r < 5; ++r) {
      const size_t o = ((size_t)(r * 10 + s) * 64 + lane) * 8;
      const v8s ah = *(const v8s*)(W2Bhi + o);
      const v8s al = *(const v8s*)(W2Blo + o);
      acc[r] = MFMA(ah, bh, acc[r]);
      acc[r] = MFMA(al, bh, acc[r]);
      acc[r] = MFMA(ah, bl, acc[r]);
    }
  }

  float part = 0.f;
#pragma unroll
  for (int r = 0; r < 5; ++r) {
#pragma unroll
    for (int q = 0; q < 16; ++q) {
      const int h2 = r * 32 + (q & 3) + 8 * (q >> 2) + 4 * half;
      const float2 bw = b2w3[h2];
      part += fmaxf(acc[r][q] + bw.x, 0.f) * bw.y;
    }
  }
  part += __shfl_xor(part, 32);
  if (lane < 32) sOut[p0 + lane] = part + b3[0];
}

// ---------------- mid: segment softmax -> weighted -> gated g update ----------
// 256 thr: dg = t&63 owns 12 d-cols (d = dg + u*64), pg = t>>6 takes pairs st+pg::4
__global__ void mid_kernel(const float* __restrict__ g, const float* __restrict__ s1,
                           const int* __restrict__ segs, const int* __restrict__ aI,
                           const float* __restrict__ Wf, const float* __restrict__ bf,
                           float* __restrict__ g2) {
  const int m = blockIdx.x;
  const int t = threadIdx.x;  // 256
  const int st = segs[m], en = segs[m + 1], n = en - st;
  if (n == 0) {
    for (int d = t; d < GI; d += 256) g2[m * GI + d] = g[m * GI + d];
    return;
  }
  __shared__ float red[256];
  __shared__ float wred[4][GI];
  // segment max
  float mx = -INFINITY;
  for (int p = st + t; p < en; p += 256) mx = fmaxf(mx, s1[p]);
  red[t] = mx; __syncthreads();
  for (int s = 128; s > 0; s >>= 1) { if (t < s) red[t] = fmaxf(red[t], red[t + s]); __syncthreads(); }
  mx = red[0]; __syncthreads();
  // weighted partials, 4-way parallel over pairs
  const int dg = t & 63, pg = t >> 6;
  float wv[12];
#pragma unroll
  for (int u = 0; u < 12; ++u) wv[u] = 0.f;
  float esum = 0.f;
  for (int p = st + pg; p < en; p += 4) {
    const float e = expf(s1[p] - mx);
    esum += e;
    const float* gj = g + (size_t)aI[p] * GI + dg;
#pragma unroll
    for (int u = 0; u < 12; ++u) wv[u] += e * gj[u * 64];
  }
  red[t] = (dg == 0) ? esum : 0.f; __syncthreads();
  for (int s = 128; s > 0; s >>= 1) { if (t < s) red[t] += red[t + s]; __syncthreads(); }
  const float denom = red[0]; __syncthreads();
#pragma unroll
  for (int u = 0; u < 12; ++u) wred[pg][dg + u * 64] = wv[u];
  __syncthreads();
  // combine partials, gate dot
  float part = 0.f;
  float wfin[3];
#pragma unroll
  for (int u = 0; u < 3; ++u) {
    const int d = t + u * 256;
    float ws = (wred[0][d] + wred[1][d] + wred[2][d] + wred[3][d]) / denom;
    wfin[u] = ws;
    part += g[(size_t)m * GI + d] * Wf[d] + ws * Wf[GI + d];
  }
  red[t] = part; __syncthreads();
  for (int s = 128; s > 0; s >>= 1) { if (t < s) red[t] += red[t + s]; __syncthreads(); }
  const float f = 1.f / (1.f + expf(-(red[0] + bf[0])));
#pragma unroll
  for (int u = 0; u < 3; ++u) {
    const int d = t + u * 256;
    g2[(size_t)m * GI + d] = f * (float)m + (1.f - f) * wfin[u];
  }
}

// ---------------- coref_scores[p] = ms[i] + ms[j] + s2[p] ---------------------
__global__ void coref_kernel(const float* __restrict__ ms, const float* __restrict__ s2,
                             const int* __restrict__ mI, const int* __restrict__ aI,
                             float* __restrict__ out, int P) {
  int p = blockIdx.x * 256 + threadIdx.x;
  if (p >= P) return;
  out[p] = ms[mI[p]] + ms[aI[p]] + s2[p];
}

// ---------------- final segment softmax with epsilon --------------------------
__global__ void final_kernel(const float* __restrict__ c, const int* __restrict__ segs,
                             float* __restrict__ pairP, float* __restrict__ epsP) {
  const int m = blockIdx.x;
  const int t = threadIdx.x;  // 256
  const int st = segs[m], en = segs[m + 1], n = en - st;
  __shared__ float red[256];
  float mx = -INFINITY;
  for (int p = st + t; p < en; p += 256) mx = fmaxf(mx, c[p]);
  red[t] = mx; __syncthreads();
  for (int s = 128; s > 0; s >>= 1) { if (t < s) red[t] = fmaxf(red[t], red[t + s]); __syncthreads(); }
  mx = red[0]; __syncthreads();
  const float m2 = (n > 0) ? fmaxf(mx, 0.f) : 0.f;
  float sm = 0.f;
  for (int p = st + t; p < en; p += 256) sm += expf(c[p] - m2);
  red[t] = sm; __syncthreads();
  for (int s = 128; s > 0; s >>= 1) { if (t < s) red[t] += red[t + s]; __syncthreads(); }
  const float denom = red[0] + expf(-m2);
  for (int p = st + t; p < en; p += 256) pairP[p] = expf(c[p] - m2) / denom;
  if (t == 0) epsP[m] = expf(-m2) / denom;
}

extern "C" void kernel_launch(void* const* d_in, const int* in_sizes, int n_in,
                              void* d_out, int out_size, void* d_ws, size_t ws_size,
                              hipStream_t stream) {
  const float* g_i  = (const float*)d_in[0];
  const float* ms   = (const float*)d_in[1];
  const int*   mI   = (const int*)d_in[2];
  const int*   aI   = (const int*)d_in[3];
  const int*   db   = (const int*)d_in[4];
  const int*   ge   = (const int*)d_in[5];
  const int*   sp   = (const int*)d_in[6];
  const float* de   = (const float*)d_in[7];
  const float* gemb = (const float*)d_in[8];
  const float* semb = (const float*)d_in[9];
  const float* W1   = (const float*)d_in[10];
  const float* b1   = (const float*)d_in[11];
  const float* W2   = (const float*)d_in[12];
  const float* b2   = (const float*)d_in[13];
  const float* W3   = (const float*)d_in[14];
  const float* b3   = (const float*)d_in[15];
  const float* Wf   = (const float*)d_in[16];
  const float* bf   = (const float*)d_in[17];

  const int S = in_sizes[0] / GI;
  const int P = in_sizes[2];
  float* out = (float*)d_out;                 // [coref P | pairP P | epsP S]

  char* ws = (char*)d_ws;
  size_t off = 0;
  auto take = [&](size_t bytes) -> char* {
    char* p = ws + off;
    off = (off + bytes + 15) & ~(size_t)15;
    return p;
  };
  int*    segs  = (int*)   take((size_t)(S + 1) * 4);
  float*  phiW  = (float*) take((size_t)21 * HPAD * 4);
  float*  pre   = (float*) take((size_t)S * 320 * 4);
  float*  g2    = (float*) take((size_t)S * GI * 4);
  float*  s1    = (float*) take((size_t)P * 4);
  float*  s2    = (float*) take((size_t)P * 4);
  ushort* WS    = (ushort*)take((size_t)NWS * 2);
  ushort* W16hi = (ushort*)take((size_t)NW16 * 2);
  ushort* W16lo = (ushort*)take((size_t)NW16 * 2);
  ushort* W2Bhi = (ushort*)take((size_t)NW2B * 2);
  ushort* W2Blo = (ushort*)take((size_t)NW2B * 2);
  float*  b1p   = (float*) take((size_t)HPAD * 4);
  float2* b2w3  = (float2*)take((size_t)HPAD * 8);
  ushort* h1hi  = (ushort*)take((size_t)P * 160 * 2);
  ushort* h1lo  = (ushort*)take((size_t)P * 160 * 2);

  const int gridSeg = (S + 1 + 255) / 256;
  const int gridPhi = (21 * HPAD + 255) / 256;
  const int padTot  = NWS + NW16 + NW2B + 2 * HPAD;
  const int gridPad = (padTot + 255) / 256;
  const dim3 gridPre(20, (S + 15) / 16);
  const int gridH   = P / 128;         // P % 128 == 0 (80000/128 = 625)
  const int gridS3  = P / 32;
  const int gridCor = (P + 255) / 256;

  seg_kernel<<<gridSeg, 256, 0, stream>>>(mI, segs, P, S);
  phi_kernel<<<gridPhi, 256, 0, stream>>>(de, gemb, semb, W1, phiW);
  pad2_kernel<<<gridPad, 256, 0, stream>>>(W1, W2, b1, b2, W3, WS,
                                           W16hi, W16lo, W2Bhi, W2Blo, b1p, b2w3);

  // iteration 1 (g = g_i)
  pre3_kernel<<<gridPre, 64, 0, stream>>>(g_i, W16hi, W16lo, pre, S);
  h1b_kernel<<<gridH, 256, 0, stream>>>(g_i, pre, phiW, WS, b1p,
                                        mI, aI, db, ge, sp, h1hi, h1lo, P);
  score3_kernel<<<gridS3, 64, 0, stream>>>(h1hi, h1lo, W2Bhi, W2Blo, b2w3, b3, s1, P);
  mid_kernel<<<S, 256, 0, stream>>>(g_i, s1, segs, aI, Wf, bf, g2);

  // iteration 2 (g = g2)
  pre3_kernel<<<gridPre, 64, 0, stream>>>(g2, W16hi, W16lo, pre, S);
  h1b_kernel<<<gridH, 256, 0, stream>>>(g2, pre, phiW, WS, b1p,
                                        mI, aI, db, ge, sp, h1hi, h1lo, P);
  score3_kernel<<<gridS3, 64, 0, stream>>>(h1hi, h1lo, W2Bhi, W2Blo, b2w3, b3, s2, P);

  // outputs
  coref_kernel<<<gridCor, 256, 0, stream>>>(ms, s2, mI, aI, out, P);
  final_kernel<<<S, 256, 0, stream>>>(out, segs, out + P, out + 2 * (size_t)P);
}